// Round 1
// baseline (580.106 us; speedup 1.0000x reference)
//
#include <hip/hip_runtime.h>
#include <hip/hip_bf16.h>

#define VOCAB 12149
#define EMB 50
#define TAGS 9
#define HID 128
#define START_TOK 7
#define BSZ 256
#define TLEN 512

__device__ __forceinline__ float tanh_fast(float x) {
  // tanh(x) = 1 - 2/(exp(2x)+1); exact identity, native exp+rcp.
  float e = __expf(2.0f * x);               // v_exp_f32
  return 1.0f - 2.0f * __builtin_amdgcn_rcpf(e + 1.0f);  // v_rcp_f32
}

// exw[v][j] = sum_e emb[v][e] * enc_Wx[e][j] + enc_b[j]
__global__ __launch_bounds__(128) void exw_kernel(
    const float* __restrict__ emb, const float* __restrict__ Wx,
    const float* __restrict__ bv, float* __restrict__ exw)
{
  __shared__ float wx_s[EMB * HID];   // 25.6 KB
  __shared__ float emb_s[8 * EMB];
  const int tid = threadIdx.x;
  const int v0 = blockIdx.x * 8;
  for (int idx = tid; idx < EMB * HID; idx += 128) wx_s[idx] = Wx[idx];
  for (int idx = tid; idx < 8 * EMB; idx += 128) {
    int r = idx / EMB;
    int e = idx - r * EMB;
    int v = v0 + r;
    emb_s[idx] = (v < VOCAB) ? emb[v * EMB + e] : 0.0f;
  }
  __syncthreads();
  const float bj = bv[tid];
  for (int r = 0; r < 8; ++r) {
    int v = v0 + r;
    if (v >= VOCAB) break;
    float acc = bj;
#pragma unroll
    for (int e = 0; e < EMB; ++e) acc += emb_s[r * EMB + e] * wx_s[e * HID + tid];
    exw[v * HID + tid] = acc;
  }
}

// One workgroup per batch row. 512 threads: thread i -> (j = i>>2, q = i&3).
// Each thread holds Wh[q*32+kk][j] (kk=0..31) for enc and dec in registers.
__global__ __launch_bounds__(512) void rnn_kernel(
    const int* __restrict__ inputs, const int* __restrict__ labels,
    const float* __restrict__ exw,
    const float* __restrict__ encWh,
    const float* __restrict__ dembG, const float* __restrict__ decWx,
    const float* __restrict__ decWh, const float* __restrict__ decb,
    const float* __restrict__ W, const float* __restrict__ bout,
    float* __restrict__ out)
{
  __shared__ float h_s[2][HID];
  __shared__ int tok_s[TLEN];
  __shared__ int lab_s[TLEN];
  __shared__ float dxw_s[TAGS * HID];
  __shared__ float demb_s[TAGS * EMB];

  const int i = threadIdx.x;
  const int j = i >> 2;
  const int q = i & 3;
  const int bidx = blockIdx.x;

  // ---- stage per-row token/label streams + decoder embedding ----
  tok_s[i] = inputs[bidx * TLEN + i];
  lab_s[i] = labels[bidx * TLEN + i];
  if (i < TAGS * EMB) demb_s[i] = dembG[i];
  if (i < HID) h_s[0][i] = 0.0f;

  // ---- Wh matrices into registers ----
  float whE[32], whD[32];
#pragma unroll
  for (int kk = 0; kk < 32; ++kk) {
    whE[kk] = encWh[(q * 32 + kk) * HID + j];
    whD[kk] = decWh[(q * 32 + kk) * HID + j];
  }

  // ---- output-projection registers (threads 0..287: o = i>>5, part = i&31) ----
  const int oo = i >> 5;
  const int part = i & 31;
  float wq0 = 0.f, wq1 = 0.f, wq2 = 0.f, wq3 = 0.f, bo = 0.f;
  if (i < TAGS * 32) {
    wq0 = W[(part * 4 + 0) * TAGS + oo];
    wq1 = W[(part * 4 + 1) * TAGS + oo];
    wq2 = W[(part * 4 + 2) * TAGS + oo];
    wq3 = W[(part * 4 + 3) * TAGS + oo];
    bo = bout[oo];
  }
  __syncthreads();

  // ---- dxw[tag][j2] = dec_emb[tag] @ dec_Wx + dec_b (9*128 tasks over 512 threads) ----
  for (int task = i; task < TAGS * HID; task += 512) {
    int tag = task >> 7;
    int j2 = task & 127;
    float acc = decb[j2];
#pragma unroll
    for (int e = 0; e < EMB; ++e) acc += demb_s[tag * EMB + e] * decWx[e * HID + j2];
    dxw_s[tag * HID + j2] = acc;
  }
  __syncthreads();

  int cur = 0;

  // ======== encoder: h = tanh(exw[tok] + h @ Wh_enc) ========
  float xvA = exw[tok_s[0] * HID + j];
  float xvB = exw[tok_s[1] * HID + j];
  for (int t = 0; t < TLEN; ++t) {
    int tn = (t + 2 < TLEN) ? (t + 2) : (TLEN - 1);
    float xvC = exw[tok_s[tn] * HID + j];   // prefetch 2 ahead

    float acc = (q == 0) ? xvA : 0.0f;
    const float4* h4 = (const float4*)(&h_s[cur][q * 32]);
#pragma unroll
    for (int kk = 0; kk < 8; ++kk) {
      float4 hv = h4[kk];
      acc += hv.x * whE[kk * 4 + 0];
      acc += hv.y * whE[kk * 4 + 1];
      acc += hv.z * whE[kk * 4 + 2];
      acc += hv.w * whE[kk * 4 + 3];
    }
    acc += __shfl_xor(acc, 1);
    acc += __shfl_xor(acc, 2);
    float hnew = tanh_fast(acc);
    if (q == 0) h_s[cur ^ 1][j] = hnew;
    __syncthreads();
    cur ^= 1;
    xvA = xvB;
    xvB = xvC;
  }

  // ======== decoder: h = tanh(dxw[lab] + h @ Wh_dec); out = h @ W + b ========
  for (int t = 0; t < TLEN; ++t) {
    int lab = (t == 0) ? START_TOK : lab_s[t - 1];
    float xv = dxw_s[lab * HID + j];

    float acc = (q == 0) ? xv : 0.0f;
    const float4* h4 = (const float4*)(&h_s[cur][q * 32]);
#pragma unroll
    for (int kk = 0; kk < 8; ++kk) {
      float4 hv = h4[kk];
      acc += hv.x * whD[kk * 4 + 0];
      acc += hv.y * whD[kk * 4 + 1];
      acc += hv.z * whD[kk * 4 + 2];
      acc += hv.w * whD[kk * 4 + 3];
    }
    acc += __shfl_xor(acc, 1);
    acc += __shfl_xor(acc, 2);
    float hnew = tanh_fast(acc);
    if (q == 0) h_s[cur ^ 1][j] = hnew;
    __syncthreads();

    // fused output projection reading the just-published h_s[cur^1]
    if (i < TAGS * 32) {
      const float4 hv = *(const float4*)(&h_s[cur ^ 1][part * 4]);
      float a2 = hv.x * wq0 + hv.y * wq1 + hv.z * wq2 + hv.w * wq3;
      a2 += __shfl_xor(a2, 1);
      a2 += __shfl_xor(a2, 2);
      a2 += __shfl_xor(a2, 4);
      a2 += __shfl_xor(a2, 8);
      a2 += __shfl_xor(a2, 16);
      if (part == 0) out[(bidx * TLEN + t) * TAGS + oo] = a2 + bo;
    }
    cur ^= 1;
  }
}

extern "C" void kernel_launch(void* const* d_in, const int* in_sizes, int n_in,
                              void* d_out, int out_size, void* d_ws, size_t ws_size,
                              hipStream_t stream) {
  const int* inputs   = (const int*)d_in[0];
  const int* labels   = (const int*)d_in[1];
  const float* emb    = (const float*)d_in[2];
  const float* encWx  = (const float*)d_in[3];
  const float* encWh  = (const float*)d_in[4];
  const float* encb   = (const float*)d_in[5];
  const float* demb   = (const float*)d_in[6];
  const float* decWx  = (const float*)d_in[7];
  const float* decWh  = (const float*)d_in[8];
  const float* decb   = (const float*)d_in[9];
  const float* W      = (const float*)d_in[10];
  const float* bo     = (const float*)d_in[11];
  float* out = (float*)d_out;

  float* exw = (float*)d_ws;  // VOCAB*HID floats = 6.22 MB

  exw_kernel<<<(VOCAB + 7) / 8, 128, 0, stream>>>(emb, encWx, encb, exw);
  rnn_kernel<<<BSZ, 512, 0, stream>>>(inputs, labels, exw, encWh,
                                      demb, decWx, decWh, decb, W, bo, out);
}